// Round 3
// baseline (1653.529 us; speedup 1.0000x reference)
//
#include <hip/hip_runtime.h>

// Ocean advection + 3x3 binomial smoothing, 48 steps, fp32.
//
// Temporal fusion x2 (two advect+smooth steps per kernel, intermediates in
// registers). ROUND-3 CHANGE: 1-row-per-stage skew with TWO lgkm-only
// barriers per iteration (was 2-row skew, one barrier). Loop shrinks
// SH2+12 -> SH2+6, so SH2=8 keeps the 1.75x halo-overhead ratio while the
// grid doubles to 1024 blocks -> 4 blocks/CU, 16 waves/CU (was 2 blocks/CU,
// 8 waves/CU). Evidence: barrier-free 16-wave/CU kernel sustained ~5.5 TB/s
// fabric; the 8-wave fused kernel only 3.0 TB/s at 18% occupancy ->
// latency/MLP-bound, so concurrency is the lever.
// Also: register FIFOs reuse ug/vg (A1+A2 uses, 2 iters apart) and mask
// (4 uses) -> global loads drop 9 -> 4 float4 per iteration.
//
// Per iteration j (full unroll, ring indices compile-time since h0%8==0):
//   loads: T row a+2 (prefetch), ug/vg row a+1 (prefetch), mask row a
//   A1 = advect(T)    at row a = h0-3+j   -> publish edge; B1
//   S1 = smooth(A1)   at row a-1          -> publish edge
//   A2 = advect(S1)   at row a-2          -> publish edge; B2
//   out= smooth(A2)   at row a-3          -> global store
// Cross-wave edge reads are separated from their publishes by >=1 barrier;
// ring depth 8 gives >=4-barrier WAR distance. Barriers are raw s_barrier
// with lgkmcnt(0) only -> global prefetches stay in flight.

#define DEG2RAD 0.017453292519943295f
#define R_EARTH 6371000.0f
#define DT_S 600.0f

constexpr int NT    = 256;   // threads per block
constexpr int STRIP = 8;     // legacy stream kernel: rows per wave
constexpr int WPW   = 256;   // legacy stream kernel: cols per wave

__global__ __launch_bounds__(256)
void prep_kernel(const float* __restrict__ lat, const float* __restrict__ lon,
                 float* __restrict__ coef, int H) {
    int h = blockIdx.x * blockDim.x + threadIdx.x;
    if (h < H) {
        float dlon = lon[1] - lon[0];
        coef[h] = 1.0f / (R_EARTH * DEG2RAD * dlon * cosf(lat[h] * DEG2RAD));
    }
    if (h == 0) {
        float dlat = lat[1] - lat[0];
        coef[H] = 1.0f / (R_EARTH * DEG2RAD * dlat);
    }
}

// ------------------------- fused 2-step kernel -----------------------------
constexpr int FWAVES = 4;    // waves per block, FWAVES*256 must == W
constexpr int SH2    = 8;    // output rows per block chunk (h0 % 8 == 0!)
constexpr int NITER  = SH2 + 6;

__global__ __launch_bounds__(256, 4)
void fused2_kernel(const float* __restrict__ Tin, const float* __restrict__ ug,
                   const float* __restrict__ vg, const float* __restrict__ mask,
                   const float* __restrict__ coef, float* __restrict__ Tout,
                   int H, int W) {
    const int lane = threadIdx.x & 63;
    const int wv   = threadIdx.x >> 6;
    const int h0   = blockIdx.x * SH2;
    const int b    = blockIdx.y;
    const int gw   = (wv << 8) + (lane << 2);
    const size_t plane = (size_t)H * W;
    const float* __restrict__ Tb  = Tin + b * plane;
    const float* __restrict__ ugb = ug  + b * plane;
    const float* __restrict__ vgb = vg  + b * plane;
    float* __restrict__ To = Tout + b * plane;
    const float inv_dy = coef[H];
    const bool isL = (lane == 0), isR = (lane == 63);
    const bool domL = (wv == 0), domR = (wv == FWAVES - 1);

    // edge rings: [row mod 8][wave][0 = first col, 1 = last col]
    __shared__ float eT [8][FWAVES][2];
    __shared__ float eA1[8][FWAVES][2];
    __shared__ float eS1[8][FWAVES][2];
    __shared__ float eA2[8][FWAVES][2];

    auto rowc = [&](int r) { return min(max(r, 0), H - 1); };
    auto ld4 = [&](const float* __restrict__ p, int r) -> float4 {
        return *(const float4*)(p + (size_t)rowc(r) * W + gw);
    };
    const float4 z4 = make_float4(0.f, 0.f, 0.f, 0.f);

    // ---- warm-up: t-chain holds rows (a-2, a-1, a+? ) pre-roll ----
    float4 t0 = z4;
    float4 t1 = ld4(Tb, h0 - 4);
    float4 t2 = ld4(Tb, h0 - 3);
    float4 t3 = ld4(Tb, h0 - 2);
    float4 u_pf = ld4(ugb, h0 - 3), g_pf = ld4(vgb, h0 - 3);
    float4 u_a = z4, u_b = z4, u_c = z4;
    float4 g_a = z4, g_b = z4, g_c = z4;
    float4 m_a = z4, m_b = z4, m_c = z4, m_d = z4;
    float4 a1p = z4, a1c = z4, a1n = z4;
    float4 s1p = z4, s1c = z4, s1n = z4;
    float4 a2p = z4, a2c = z4, a2n = z4;

    // pre-publish T edges for rows h0-3 (ring 5), h0-2 (ring 6)  [h0%8==0]
    if (isL) { eT[5][wv][0] = t2.x; eT[6][wv][0] = t3.x; }
    if (isR) { eT[5][wv][1] = t2.w; eT[6][wv][1] = t3.w; }
    asm volatile("s_waitcnt lgkmcnt(0)" ::: "memory");
    __builtin_amdgcn_s_barrier();

    #pragma unroll
    for (int j = 0; j < NITER; ++j) {
        const int a = h0 - 3 + j;               // A1 row
        const int s = a - 1, q = a - 2, r = a - 3;
        // ring indices (compile-time under unroll; h0 % 8 == 0)
        const int rgA  = (j + 5) & 7;           // row a
        const int rgA1 = (j + 6) & 7;           // row a+1
        const int rgS  = (j + 4) & 7;           // row s
        const int rgQ  = (j + 3) & 7;           // row q
        const int rgR  = (j + 2) & 7;           // row r
        const int rgRm = (j + 1) & 7;           // row r-1

        // ---- roll T chain + FIFOs, issue loads ----
        t0 = t1; t1 = t2; t2 = t3;
        t3 = ld4(Tb, a + 2);                    // prefetch (used next iter)
        u_c = u_b; u_b = u_a; u_a = u_pf; u_pf = ld4(ugb, a + 1);
        g_c = g_b; g_b = g_a; g_a = g_pf; g_pf = ld4(vgb, a + 1);
        m_d = m_c; m_c = m_b; m_b = m_a; m_a = ld4(mask, a);  // mask: L2-hot

        // publish T edges for row a+1 (t2: completed load)
        if (isL) eT[rgA1][wv][0] = t2.x;
        if (isR) eT[rgA1][wv][1] = t2.w;

        // ---------------- A1: advect T at row a ----------------
        float4 a1_new = z4;
        if (a >= 0 && a < H) {
            const float ix  = coef[a];
            const float sy  = (a == 0 || a == H - 1) ? inv_dy : 0.5f * inv_dy;
            const float sxh = 0.5f * ix;
            float cL = __shfl_up(t1.w, 1);
            float cR = __shfl_down(t1.x, 1);
            float sxx = sxh, sxw = sxh;
            if (isL) { if (domL) { cL = t1.x; sxx = ix; } else cL = eT[rgA][wv - 1][1]; }
            if (isR) { if (domR) { cR = t1.w; sxw = ix; } else cR = eT[rgA][wv + 1][0]; }
            a1_new.x = t1.x + DT_S * (-(u_a.x * ((t1.y - cL ) * sxx) + g_a.x * ((t2.x - t0.x) * sy)) * m_a.x);
            a1_new.y = t1.y + DT_S * (-(u_a.y * ((t1.z - t1.x) * sxh) + g_a.y * ((t2.y - t0.y) * sy)) * m_a.y);
            a1_new.z = t1.z + DT_S * (-(u_a.z * ((t1.w - t1.y) * sxh) + g_a.z * ((t2.z - t0.z) * sy)) * m_a.z);
            a1_new.w = t1.w + DT_S * (-(u_a.w * ((cR  - t1.z) * sxw) + g_a.w * ((t2.w - t0.w) * sy)) * m_a.w);
        }
        if (isL) eA1[rgA][wv][0] = a1_new.x;
        if (isR) eA1[rgA][wv][1] = a1_new.w;
        a1n = a1_new;

        // B1: A1 edges visible; global prefetches stay in flight
        asm volatile("s_waitcnt lgkmcnt(0)" ::: "memory");
        __builtin_amdgcn_s_barrier();

        // ---------------- S1: smooth A1 at row s ----------------
        float4 s1_new = z4;
        if (j >= 2) {
            if (s >= 0 && s < H) {
                float4 v;
                v.x = a1p.x + 2.f * a1c.x + a1n.x;
                v.y = a1p.y + 2.f * a1c.y + a1n.y;
                v.z = a1p.z + 2.f * a1c.z + a1n.z;
                v.w = a1p.w + 2.f * a1c.w + a1n.w;
                float vL = __shfl_up(v.w, 1);
                float vR = __shfl_down(v.x, 1);
                if (isL) vL = domL ? 0.f
                    : (eA1[rgQ][wv - 1][1] + 2.f * eA1[rgS][wv - 1][1] + eA1[rgA][wv - 1][1]);
                if (isR) vR = domR ? 0.f
                    : (eA1[rgQ][wv + 1][0] + 2.f * eA1[rgS][wv + 1][0] + eA1[rgA][wv + 1][0]);
                s1_new.x = (vL  + 2.f * v.x + v.y) * 0.0625f * m_b.x;
                s1_new.y = (v.x + 2.f * v.y + v.z) * 0.0625f * m_b.y;
                s1_new.z = (v.y + 2.f * v.z + v.w) * 0.0625f * m_b.z;
                s1_new.w = (v.z + 2.f * v.w + vR ) * 0.0625f * m_b.w;
            }
            if (isL) eS1[rgS][wv][0] = s1_new.x;
            if (isR) eS1[rgS][wv][1] = s1_new.w;
        }
        a1p = a1c; a1c = a1n;
        s1n = s1_new;

        // ---------------- A2: advect S1 at row q ----------------
        float4 a2_new = z4;
        if (j >= 4) {
            if (q >= 0 && q < H) {
                const float ix  = coef[q];
                const float sxh = 0.5f * ix;
                float cL = __shfl_up(s1c.w, 1);
                float cR = __shfl_down(s1c.x, 1);
                float sxx = sxh, sxw = sxh;
                if (isL) { if (domL) { cL = s1c.x; sxx = ix; } else cL = eS1[rgQ][wv - 1][1]; }
                if (isR) { if (domR) { cR = s1c.w; sxw = ix; } else cR = eS1[rgQ][wv + 1][0]; }
                const float4 yl = (q == 0)     ? s1c : s1p;
                const float4 yh = (q == H - 1) ? s1c : s1n;
                const float sy  = (q == 0 || q == H - 1) ? inv_dy : 0.5f * inv_dy;
                a2_new.x = s1c.x + DT_S * (-(u_c.x * ((s1c.y - cL  ) * sxx) + g_c.x * ((yh.x - yl.x) * sy)) * m_c.x);
                a2_new.y = s1c.y + DT_S * (-(u_c.y * ((s1c.z - s1c.x) * sxh) + g_c.y * ((yh.y - yl.y) * sy)) * m_c.y);
                a2_new.z = s1c.z + DT_S * (-(u_c.z * ((s1c.w - s1c.y) * sxh) + g_c.z * ((yh.z - yl.z) * sy)) * m_c.z);
                a2_new.w = s1c.w + DT_S * (-(u_c.w * ((cR   - s1c.z) * sxw) + g_c.w * ((yh.w - yl.w) * sy)) * m_c.w);
            }
            if (isL) eA2[rgQ][wv][0] = a2_new.x;
            if (isR) eA2[rgQ][wv][1] = a2_new.w;
        }
        s1p = s1c; s1c = s1n;
        a2n = a2_new;

        // B2: A2 edges visible
        asm volatile("s_waitcnt lgkmcnt(0)" ::: "memory");
        __builtin_amdgcn_s_barrier();

        // ---------------- out: smooth A2 at row r ----------------
        if (j >= 6) {
            if (r < H) {
                float4 v;
                v.x = a2p.x + 2.f * a2c.x + a2n.x;
                v.y = a2p.y + 2.f * a2c.y + a2n.y;
                v.z = a2p.z + 2.f * a2c.z + a2n.z;
                v.w = a2p.w + 2.f * a2c.w + a2n.w;
                float vL = __shfl_up(v.w, 1);
                float vR = __shfl_down(v.x, 1);
                if (isL) vL = domL ? 0.f
                    : (eA2[rgRm][wv - 1][1] + 2.f * eA2[rgR][wv - 1][1] + eA2[rgQ][wv - 1][1]);
                if (isR) vR = domR ? 0.f
                    : (eA2[rgRm][wv + 1][0] + 2.f * eA2[rgR][wv + 1][0] + eA2[rgQ][wv + 1][0]);
                float4 o;
                o.x = (vL  + 2.f * v.x + v.y) * 0.0625f * m_d.x;
                o.y = (v.x + 2.f * v.y + v.z) * 0.0625f * m_d.y;
                o.z = (v.y + 2.f * v.z + v.w) * 0.0625f * m_d.z;
                o.w = (v.z + 2.f * v.w + vR ) * 0.0625f * m_d.w;
                *(float4*)(To + (size_t)r * W + gw) = o;
            }
        }
        a2p = a2c; a2c = a2n;
    }
}

// --------- legacy single-step stream kernel (fallback, W % 256 == 0) -------
__global__ __launch_bounds__(256, 4)
void stream_kernel(const float* __restrict__ Tin, const float* __restrict__ ug,
                   const float* __restrict__ vg, const float* __restrict__ mask,
                   const float* __restrict__ coef, float* __restrict__ Tout,
                   int H, int W) {
    const int lane = threadIdx.x & 63;
    const int wv   = threadIdx.x >> 6;
    const int ws   = blockIdx.x * WPW;
    const int hs   = (blockIdx.y * 4 + wv) * STRIP;
    const int b    = blockIdx.z;
    if (hs >= H) return;
    const size_t plane = (size_t)H * W;
    const float* __restrict__ Tb  = Tin + b * plane;
    const float* __restrict__ ugb = ug  + b * plane;
    const float* __restrict__ vgb = vg  + b * plane;
    float* __restrict__ To = Tout + b * plane;
    const float inv_dy = coef[H];
    const bool atL = (ws == 0);
    const bool atR = (ws + WPW >= W);
    const bool isL = (lane == 0);
    const bool isR = (lane == 63);
    const int gw = ws + 4 * lane;

    auto clampr = [&](int r) { return min(max(r, 0), H - 1); };
    auto ldT = [&](int r) -> float4 {
        return *(const float4*)(Tb + (size_t)clampr(r) * W + gw);
    };
    auto ldL = [&](int r) -> float2 {
        float4 q = *(const float4*)(Tb + (size_t)clampr(r) * W + (ws - 4));
        return make_float2(q.z, q.w);
    };
    auto ldR = [&](int r) -> float2 {
        float4 q = *(const float4*)(Tb + (size_t)clampr(r) * W + (ws + WPW));
        return make_float2(q.x, q.y);
    };

    float4 tp, tc, tn;
    float  tLp_w = 0.f; float2 tLc = make_float2(0.f, 0.f), tLn = make_float2(0.f, 0.f);
    float  tRp_x = 0.f; float2 tRc = make_float2(0.f, 0.f), tRn = make_float2(0.f, 0.f);

    auto roll = [&](int rnext) {
        tp = tc; tc = tn; tn = ldT(rnext);
        if (!atL) { tLp_w = tLc.y; tLc = tLn; tLn = ldL(rnext); }
        if (!atR) { tRp_x = tRc.x; tRc = tRn; tRn = ldR(rnext); }
    };

    auto advrow = [&](int r, float4& a, float& aL, float& aR, float4& mOut) {
        if (r < 0 || r >= H) {
            a = make_float4(0.f, 0.f, 0.f, 0.f); aL = 0.f; aR = 0.f;
            mOut = make_float4(0.f, 0.f, 0.f, 0.f); return;
        }
        const size_t ro = (size_t)r * W;
        const float ix  = coef[r];
        const float sy  = (r == 0 || r == H - 1) ? inv_dy : 0.5f * inv_dy;
        const float sxh = 0.5f * ix;
        float4 u4 = *(const float4*)(ugb + ro + gw);
        float4 g4 = *(const float4*)(vgb + ro + gw);
        float4 m4 = *(const float4*)(mask + ro + gw);
        float cLw = __shfl_up(tc.w, 1);
        float cRx = __shfl_down(tc.x, 1);
        float sxx = sxh, sxw = sxh;
        if (isL) { if (atL) { cLw = tc.x; sxx = ix; } else { cLw = tLc.y; } }
        if (isR) { if (atR) { cRx = tc.w; sxw = ix; } else { cRx = tRc.x; } }
        a.x = tc.x + DT_S * (-(u4.x * ((tc.y - cLw) * sxx) + g4.x * ((tn.x - tp.x) * sy)) * m4.x);
        a.y = tc.y + DT_S * (-(u4.y * ((tc.z - tc.x) * sxh) + g4.y * ((tn.y - tp.y) * sy)) * m4.y);
        a.z = tc.z + DT_S * (-(u4.z * ((tc.w - tc.y) * sxh) + g4.z * ((tn.z - tp.z) * sy)) * m4.z);
        a.w = tc.w + DT_S * (-(u4.w * ((cRx - tc.z) * sxw) + g4.w * ((tn.w - tp.w) * sy)) * m4.w);
        if (!atL) {
            float uL = ((const float4*)(ugb + ro + (ws - 4)))->w;
            float gL = ((const float4*)(vgb + ro + (ws - 4)))->w;
            float mL = ((const float4*)(mask + ro + (ws - 4)))->w;
            aL = tLc.y + DT_S * (-(uL * ((tc.x - tLc.x) * sxh) + gL * ((tLn.y - tLp_w) * sy)) * mL);
        } else aL = 0.f;
        if (!atR) {
            float uR = ((const float4*)(ugb + ro + (ws + WPW)))->x;
            float gR = ((const float4*)(vgb + ro + (ws + WPW)))->x;
            float mR = ((const float4*)(mask + ro + (ws + WPW)))->x;
            aR = tRc.x + DT_S * (-(uR * ((tRc.y - tc.w) * sxh) + gR * ((tRn.x - tRp_x) * sy)) * mR);
        } else aR = 0.f;
        mOut = m4;
    };

    tp = ldT(hs - 2); tc = ldT(hs - 1); tn = ldT(hs);
    if (!atL) { float2 q = ldL(hs - 2); tLp_w = q.y; tLc = ldL(hs - 1); tLn = ldL(hs); }
    if (!atR) { float2 q = ldR(hs - 2); tRp_x = q.x; tRc = ldR(hs - 1); tRn = ldR(hs); }

    float4 ap, ac, an, mC, mN, mdum;
    float aLp, aLc, aLn, aRp, aRc, aRn;
    advrow(hs - 1, ap, aLp, aRp, mdum);
    roll(hs + 1);
    advrow(hs, ac, aLc, aRc, mC);

    #pragma unroll
    for (int i = 0; i < STRIP; ++i) {
        const int go = hs + i;
        roll(go + 2);
        advrow(go + 1, an, aLn, aRn, mN);
        if (go < H) {
            float4 v;
            v.x = ap.x + 2.f * ac.x + an.x;
            v.y = ap.y + 2.f * ac.y + an.y;
            v.z = ap.z + 2.f * ac.z + an.z;
            v.w = ap.w + 2.f * ac.w + an.w;
            float vL  = aLp + 2.f * aLc + aLn;
            float vR  = aRp + 2.f * aRc + aRn;
            float vLw = __shfl_up(v.w, 1);
            float vRx = __shfl_down(v.x, 1);
            if (isL) vLw = atL ? 0.f : vL;
            if (isR) vRx = atR ? 0.f : vR;
            float4 o;
            o.x = (vLw + 2.f * v.x + v.y) * 0.0625f * mC.x;
            o.y = (v.x + 2.f * v.y + v.z) * 0.0625f * mC.y;
            o.z = (v.y + 2.f * v.z + v.w) * 0.0625f * mC.z;
            o.w = (v.z + 2.f * v.w + vRx) * 0.0625f * mC.w;
            *(float4*)(To + (size_t)go * W + gw) = o;
        }
        ap = ac; ac = an;
        aLp = aLc; aLc = aLn; aRp = aRc; aRc = aRn;
        mC = mN;
    }
}

// ---------- generic fallback (round-1 LDS tile kernel, validated) ----------
constexpr int FTW = 64, FTH = 32;
constexpr int FSTW = FTW + 4, FSTH = FTH + 4;
constexpr int FMTW = FTW + 2, FMTH = FTH + 2;

__global__ __launch_bounds__(256)
void step_tile(const float* __restrict__ Tin, const float* __restrict__ ug,
               const float* __restrict__ vg, const float* __restrict__ mask,
               const float* __restrict__ coef, float* __restrict__ Tout,
               int H, int W) {
    __shared__ float sT[FSTH][FSTW];
    __shared__ float sM[FMTH][FMTW];
    const int tid = threadIdx.x;
    const int w0 = blockIdx.x * FTW;
    const int h0 = blockIdx.y * FTH;
    const int b  = blockIdx.z;
    const long plane = (long)H * W;
    const float* Tb  = Tin + b * plane;
    const float* ugb = ug  + b * plane;
    const float* vgb = vg  + b * plane;
    const float inv_dy = coef[H];

    for (int i = tid; i < FSTH * FSTW; i += NT) {
        int r = i / FSTW, c = i - r * FSTW;
        int gh = min(max(h0 - 2 + r, 0), H - 1);
        int gw = min(max(w0 - 2 + c, 0), W - 1);
        sT[r][c] = Tb[gh * W + gw];
    }
    __syncthreads();
    for (int i = tid; i < FMTH * FMTW; i += NT) {
        int r = i / FMTW, c = i - r * FMTW;
        int gh = h0 - 1 + r, gw = w0 - 1 + c;
        float v = 0.0f;
        if (gh >= 0 && gh < H && gw >= 0 && gw < W) {
            int sr = r + 1, sc = c + 1;
            float ndy = sT[sr + 1][sc] - sT[sr - 1][sc];
            float ndx = sT[sr][sc + 1] - sT[sr][sc - 1];
            float sy  = (gh == 0 || gh == H - 1) ? inv_dy : 0.5f * inv_dy;
            float ix  = coef[gh];
            float sx  = (gw == 0 || gw == W - 1) ? ix : 0.5f * ix;
            int   gi  = gh * W + gw;
            float F   = -(ugb[gi] * (ndx * sx) + vgb[gi] * (ndy * sy)) * mask[gi];
            v = sT[sr][sc] + DT_S * F;
        }
        sM[r][c] = v;
    }
    __syncthreads();
    float* To = Tout + b * plane;
    for (int i = tid; i < FTH * FTW; i += NT) {
        int r = i >> 6, c = i & (FTW - 1);
        int gh = h0 + r, gw = w0 + c;
        if (gh < H && gw < W) {
            int sr = r + 1, sc = c + 1;
            float s = (sM[sr-1][sc-1] + sM[sr-1][sc+1] + sM[sr+1][sc-1] + sM[sr+1][sc+1])
                    + 2.0f * (sM[sr-1][sc] + sM[sr+1][sc] + sM[sr][sc-1] + sM[sr][sc+1])
                    + 4.0f * sM[sr][sc];
            To[gh * W + gw] = s * 0.0625f * mask[gh * W + gw];
        }
    }
}

extern "C" void kernel_launch(void* const* d_in, const int* in_sizes, int n_in,
                              void* d_out, int out_size, void* d_ws, size_t ws_size,
                              hipStream_t stream) {
    const float* T0   = (const float*)d_in[0];
    const float* ug   = (const float*)d_in[1];
    const float* vg   = (const float*)d_in[2];
    const float* lat  = (const float*)d_in[3];
    const float* lon  = (const float*)d_in[4];
    const float* mask = (const float*)d_in[5];

    const int H = in_sizes[3];
    const int W = in_sizes[4];
    const int B = in_sizes[0] / (H * W);

    float* out  = (float*)d_out;
    float* ping = (float*)d_ws;                 // B*H*W floats
    float* coef = ping + (size_t)B * H * W;     // H+1 floats: 1/dx[h], then 1/dy

    prep_kernel<<<dim3((H + NT - 1) / NT), dim3(NT), 0, stream>>>(lat, lon, coef, H);

    const int STEPS = 48;

    if (W == FWAVES * 256) {
        // fused 2-step path: 24 launches, each = 2 simulated steps
        dim3 gridF2((H + SH2 - 1) / SH2, B);
        for (int i = 0; i < STEPS / 2; ++i) {
            const float* src = (i == 0) ? T0 : ((i & 1) ? ping : out);
            float*       dst = (i & 1) ? out : ping;
            fused2_kernel<<<gridF2, dim3(NT), 0, stream>>>(src, ug, vg, mask, coef, dst, H, W);
        }
    } else {
        const bool fast = (W % WPW) == 0;
        dim3 gridS(W / (fast ? WPW : 1), (H + 4 * STRIP - 1) / (4 * STRIP), B);
        dim3 gridF((W + FTW - 1) / FTW, (H + FTH - 1) / FTH, B);
        for (int i = 0; i < STEPS; ++i) {
            const float* src = (i == 0) ? T0 : ((i & 1) ? ping : out);
            float*       dst = (i & 1) ? out : ping;
            if (fast)
                stream_kernel<<<gridS, dim3(NT), 0, stream>>>(src, ug, vg, mask, coef, dst, H, W);
            else
                step_tile<<<gridF, dim3(NT), 0, stream>>>(src, ug, vg, mask, coef, dst, H, W);
        }
    }
}

// Round 5
// 872.630 us; speedup vs baseline: 1.8949x; 1.8949x over previous
//
#include <hip/hip_runtime.h>

// Ocean advection + 3x3 binomial smoothing, 48 steps, fp32.
//
// TEMPORAL FUSION x3: each kernel performs THREE advect+smooth steps with
// both intermediate fields entirely in registers. 16 dispatches total.
// Unique memory traffic per simulated step is ~1/3 of the single-step kernel.
//
// ROUND-4 NOTES (from round-3 post-mortem): __launch_bounds__(256,4) forced
// VGPR=64 -> scratch spills (WRITE_SIZE 32MB->61MB, 59->87us). Registers are
// the binding constraint; keep __launch_bounds__(256,2) (VGPR cap 256, no
// spill; live state ~175 VGPR) and accept ~8 waves/CU.
// (Round-5 resubmission: round-4 bench was an infra failure, no counters.)
//
// fused3_kernel structure (1-row-per-stage skew, 3 lgkm-only barriers/iter):
//   per iteration j (a = h0-5+j), full unroll, ring idx compile-time:
//     loads: T row a+2, ug/vg row a+1, mask row a+1 (all >=1 iter ahead;
//            ug/vg FIFO depth 6, mask depth 7 - reused across stages)
//     A1 = advect(T)   @ a    -> publish edge; B1
//     S1 = smooth(A1)  @ a-1  -> publish edge
//     A2 = advect(S1)  @ a-2  -> publish edge; B2
//     S2 = smooth(A2)  @ a-3  -> publish edge
//     A3 = advect(S2)  @ a-4  -> publish edge; B3
//     out= smooth(A3)  @ a-5  -> global store
//   Cross-wave x-halo via LDS edge rings (8-row ring x wave x {first,last}
//   col); every cross-wave read is >=1 barrier after its publish; ring
//   depth 8 => WAR distance >=18 barriers. Barriers are raw s_barrier with
//   lgkmcnt(0) only -> global prefetches stay in flight.
//   SH3=16 rows/block -> NITER=26 (1.63x halo overhead), grid 512 blocks.

#define DEG2RAD 0.017453292519943295f
#define R_EARTH 6371000.0f
#define DT_S 600.0f

constexpr int NT    = 256;   // threads per block
constexpr int STRIP = 8;     // legacy stream kernel: rows per wave
constexpr int WPW   = 256;   // legacy stream kernel: cols per wave

__global__ __launch_bounds__(256)
void prep_kernel(const float* __restrict__ lat, const float* __restrict__ lon,
                 float* __restrict__ coef, int H) {
    int h = blockIdx.x * blockDim.x + threadIdx.x;
    if (h < H) {
        float dlon = lon[1] - lon[0];
        coef[h] = 1.0f / (R_EARTH * DEG2RAD * dlon * cosf(lat[h] * DEG2RAD));
    }
    if (h == 0) {
        float dlat = lat[1] - lat[0];
        coef[H] = 1.0f / (R_EARTH * DEG2RAD * dlat);
    }
}

// ------------------------- fused 3-step kernel -----------------------------
constexpr int FWAVES = 4;    // waves per block, FWAVES*256 must == W
constexpr int SH3    = 16;   // output rows per block chunk (SH3 % 8 == 0!)
constexpr int NITER3 = SH3 + 10;

__global__ __launch_bounds__(256, 2)
void fused3_kernel(const float* __restrict__ Tin, const float* __restrict__ ug,
                   const float* __restrict__ vg, const float* __restrict__ mask,
                   const float* __restrict__ coef, float* __restrict__ Tout,
                   int H, int W) {
    const int lane = threadIdx.x & 63;
    const int wv   = threadIdx.x >> 6;
    const int h0   = blockIdx.x * SH3;
    const int b    = blockIdx.y;
    const int gw   = (wv << 8) + (lane << 2);
    const size_t plane = (size_t)H * W;
    const float* __restrict__ Tb  = Tin + b * plane;
    const float* __restrict__ ugb = ug  + b * plane;
    const float* __restrict__ vgb = vg  + b * plane;
    float* __restrict__ To = Tout + b * plane;
    const float inv_dy = coef[H];
    const bool isL = (lane == 0), isR = (lane == 63);
    const bool domL = (wv == 0), domR = (wv == FWAVES - 1);

    // edge rings: [row mod 8][wave][0 = first col, 1 = last col]
    __shared__ float eT [8][FWAVES][2];
    __shared__ float eA1[8][FWAVES][2];
    __shared__ float eS1[8][FWAVES][2];
    __shared__ float eA2[8][FWAVES][2];
    __shared__ float eS2[8][FWAVES][2];
    __shared__ float eA3[8][FWAVES][2];

    auto rowc = [&](int r) { return min(max(r, 0), H - 1); };
    auto ld4 = [&](const float* __restrict__ p, int r) -> float4 {
        return *(const float4*)(p + (size_t)rowc(r) * W + gw);
    };
    const float4 z4 = make_float4(0.f, 0.f, 0.f, 0.f);

    // ---- warm-up: after the j=0 roll, t0..t3 = rows a-1..a+2 (a = h0-5) ----
    float4 t0 = z4;
    float4 t1 = ld4(Tb, h0 - 6);
    float4 t2 = ld4(Tb, h0 - 5);
    float4 t3 = ld4(Tb, h0 - 4);
    // FIFOs: slot k holds row (a+1-k) after the roll
    float4 u0 = ld4(ugb, h0 - 5), u1 = z4, u2 = z4, u3 = z4, u4 = z4, u5 = z4;
    float4 g0 = ld4(vgb, h0 - 5), g1 = z4, g2 = z4, g3 = z4, g4 = z4, g5 = z4;
    float4 m0 = ld4(mask, h0 - 5), m1 = z4, m2 = z4, m3 = z4, m4 = z4, m5 = z4, m6 = z4;
    float4 a1p = z4, a1c = z4, a1n = z4;
    float4 s1p = z4, s1c = z4, s1n = z4;
    float4 a2p = z4, a2c = z4, a2n = z4;
    float4 s2p = z4, s2c = z4, s2n = z4;
    float4 a3p = z4, a3c = z4, a3n = z4;

    // pre-publish eT for rows h0-5 (ring 3) and h0-4 (ring 4)  [h0 % 8 == 0]
    if (isL) { eT[3][wv][0] = t2.x; eT[4][wv][0] = t3.x; }
    if (isR) { eT[3][wv][1] = t2.w; eT[4][wv][1] = t3.w; }
    asm volatile("s_waitcnt lgkmcnt(0)" ::: "memory");
    __builtin_amdgcn_s_barrier();

    #pragma unroll
    for (int j = 0; j < NITER3; ++j) {
        const int a = h0 - 5 + j;               // A1 row;  a mod 8 == (j+3)&7
        const int rg_a1p = (j + 4) & 7;         // row a+1
        const int rg_a   = (j + 3) & 7;         // row a
        const int rg_am1 = (j + 2) & 7;         // row a-1
        const int rg_am2 = (j + 1) & 7;         // row a-2
        const int rg_am3 = (j + 0) & 7;         // row a-3
        const int rg_am4 = (j + 7) & 7;         // row a-4
        const int rg_am5 = (j + 6) & 7;         // row a-5
        const int rg_am6 = (j + 5) & 7;         // row a-6

        // ---- roll chains/FIFOs, issue loads (all consumed next iter) ----
        t0 = t1; t1 = t2; t2 = t3; t3 = ld4(Tb, a + 2);
        u5 = u4; u4 = u3; u3 = u2; u2 = u1; u1 = u0; u0 = ld4(ugb, a + 1);
        g5 = g4; g4 = g3; g3 = g2; g2 = g1; g1 = g0; g0 = ld4(vgb, a + 1);
        m6 = m5; m5 = m4; m4 = m3; m3 = m2; m2 = m1; m1 = m0; m0 = ld4(mask, a + 1);

        // publish T edges for row a+1 (t2: load completed last iteration)
        if (isL) eT[rg_a1p][wv][0] = t2.x;
        if (isR) eT[rg_a1p][wv][1] = t2.w;

        // ---------------- A1: advect T at row a ----------------
        float4 a1_new = z4;
        if (a >= 0 && a < H) {
            const float ix  = coef[a];
            const float sy  = (a == 0 || a == H - 1) ? inv_dy : 0.5f * inv_dy;
            const float sxh = 0.5f * ix;
            float cL = __shfl_up(t1.w, 1);
            float cR = __shfl_down(t1.x, 1);
            float sxx = sxh, sxw = sxh;
            if (isL) { if (domL) { cL = t1.x; sxx = ix; } else cL = eT[rg_a][wv - 1][1]; }
            if (isR) { if (domR) { cR = t1.w; sxw = ix; } else cR = eT[rg_a][wv + 1][0]; }
            a1_new.x = t1.x + DT_S * (-(u1.x * ((t1.y - cL ) * sxx) + g1.x * ((t2.x - t0.x) * sy)) * m1.x);
            a1_new.y = t1.y + DT_S * (-(u1.y * ((t1.z - t1.x) * sxh) + g1.y * ((t2.y - t0.y) * sy)) * m1.y);
            a1_new.z = t1.z + DT_S * (-(u1.z * ((t1.w - t1.y) * sxh) + g1.z * ((t2.z - t0.z) * sy)) * m1.z);
            a1_new.w = t1.w + DT_S * (-(u1.w * ((cR  - t1.z) * sxw) + g1.w * ((t2.w - t0.w) * sy)) * m1.w);
        }
        if (isL) eA1[rg_a][wv][0] = a1_new.x;
        if (isR) eA1[rg_a][wv][1] = a1_new.w;
        a1n = a1_new;

        // B1: A1 edges visible; global prefetches stay in flight
        asm volatile("s_waitcnt lgkmcnt(0)" ::: "memory");
        __builtin_amdgcn_s_barrier();

        // ---------------- S1: smooth A1 at row a-1 ----------------
        float4 s1_new = z4;
        if (j >= 2) {
            const int s = a - 1;
            if (s >= 0 && s < H) {
                float4 v;
                v.x = a1p.x + 2.f * a1c.x + a1n.x;
                v.y = a1p.y + 2.f * a1c.y + a1n.y;
                v.z = a1p.z + 2.f * a1c.z + a1n.z;
                v.w = a1p.w + 2.f * a1c.w + a1n.w;
                float vL = __shfl_up(v.w, 1);
                float vR = __shfl_down(v.x, 1);
                if (isL) vL = domL ? 0.f
                    : (eA1[rg_am2][wv - 1][1] + 2.f * eA1[rg_am1][wv - 1][1] + eA1[rg_a][wv - 1][1]);
                if (isR) vR = domR ? 0.f
                    : (eA1[rg_am2][wv + 1][0] + 2.f * eA1[rg_am1][wv + 1][0] + eA1[rg_a][wv + 1][0]);
                s1_new.x = (vL  + 2.f * v.x + v.y) * 0.0625f * m2.x;
                s1_new.y = (v.x + 2.f * v.y + v.z) * 0.0625f * m2.y;
                s1_new.z = (v.y + 2.f * v.z + v.w) * 0.0625f * m2.z;
                s1_new.w = (v.z + 2.f * v.w + vR ) * 0.0625f * m2.w;
            }
            if (isL) eS1[rg_am1][wv][0] = s1_new.x;
            if (isR) eS1[rg_am1][wv][1] = s1_new.w;
        }
        a1p = a1c; a1c = a1n;
        s1n = s1_new;

        // ---------------- A2: advect S1 at row a-2 ----------------
        float4 a2_new = z4;
        if (j >= 4) {
            const int q = a - 2;
            if (q >= 0 && q < H) {
                const float ix  = coef[q];
                const float sxh = 0.5f * ix;
                float cL = __shfl_up(s1c.w, 1);
                float cR = __shfl_down(s1c.x, 1);
                float sxx = sxh, sxw = sxh;
                if (isL) { if (domL) { cL = s1c.x; sxx = ix; } else cL = eS1[rg_am2][wv - 1][1]; }
                if (isR) { if (domR) { cR = s1c.w; sxw = ix; } else cR = eS1[rg_am2][wv + 1][0]; }
                const float4 yl = (q == 0)     ? s1c : s1p;
                const float4 yh = (q == H - 1) ? s1c : s1n;
                const float sy  = (q == 0 || q == H - 1) ? inv_dy : 0.5f * inv_dy;
                a2_new.x = s1c.x + DT_S * (-(u3.x * ((s1c.y - cL  ) * sxx) + g3.x * ((yh.x - yl.x) * sy)) * m3.x);
                a2_new.y = s1c.y + DT_S * (-(u3.y * ((s1c.z - s1c.x) * sxh) + g3.y * ((yh.y - yl.y) * sy)) * m3.y);
                a2_new.z = s1c.z + DT_S * (-(u3.z * ((s1c.w - s1c.y) * sxh) + g3.z * ((yh.z - yl.z) * sy)) * m3.z);
                a2_new.w = s1c.w + DT_S * (-(u3.w * ((cR   - s1c.z) * sxw) + g3.w * ((yh.w - yl.w) * sy)) * m3.w);
            }
            if (isL) eA2[rg_am2][wv][0] = a2_new.x;
            if (isR) eA2[rg_am2][wv][1] = a2_new.w;
        }
        s1p = s1c; s1c = s1n;
        a2n = a2_new;

        // B2: A2 edges visible
        asm volatile("s_waitcnt lgkmcnt(0)" ::: "memory");
        __builtin_amdgcn_s_barrier();

        // ---------------- S2: smooth A2 at row a-3 ----------------
        float4 s2_new = z4;
        if (j >= 6) {
            const int s = a - 3;
            if (s >= 0 && s < H) {
                float4 v;
                v.x = a2p.x + 2.f * a2c.x + a2n.x;
                v.y = a2p.y + 2.f * a2c.y + a2n.y;
                v.z = a2p.z + 2.f * a2c.z + a2n.z;
                v.w = a2p.w + 2.f * a2c.w + a2n.w;
                float vL = __shfl_up(v.w, 1);
                float vR = __shfl_down(v.x, 1);
                if (isL) vL = domL ? 0.f
                    : (eA2[rg_am4][wv - 1][1] + 2.f * eA2[rg_am3][wv - 1][1] + eA2[rg_am2][wv - 1][1]);
                if (isR) vR = domR ? 0.f
                    : (eA2[rg_am4][wv + 1][0] + 2.f * eA2[rg_am3][wv + 1][0] + eA2[rg_am2][wv + 1][0]);
                s2_new.x = (vL  + 2.f * v.x + v.y) * 0.0625f * m4.x;
                s2_new.y = (v.x + 2.f * v.y + v.z) * 0.0625f * m4.y;
                s2_new.z = (v.y + 2.f * v.z + v.w) * 0.0625f * m4.z;
                s2_new.w = (v.z + 2.f * v.w + vR ) * 0.0625f * m4.w;
            }
            if (isL) eS2[rg_am3][wv][0] = s2_new.x;
            if (isR) eS2[rg_am3][wv][1] = s2_new.w;
        }
        a2p = a2c; a2c = a2n;
        s2n = s2_new;

        // ---------------- A3: advect S2 at row a-4 ----------------
        float4 a3_new = z4;
        if (j >= 8) {
            const int p = a - 4;
            if (p >= 0 && p < H) {
                const float ix  = coef[p];
                const float sxh = 0.5f * ix;
                float cL = __shfl_up(s2c.w, 1);
                float cR = __shfl_down(s2c.x, 1);
                float sxx = sxh, sxw = sxh;
                if (isL) { if (domL) { cL = s2c.x; sxx = ix; } else cL = eS2[rg_am4][wv - 1][1]; }
                if (isR) { if (domR) { cR = s2c.w; sxw = ix; } else cR = eS2[rg_am4][wv + 1][0]; }
                const float4 yl = (p == 0)     ? s2c : s2p;
                const float4 yh = (p == H - 1) ? s2c : s2n;
                const float sy  = (p == 0 || p == H - 1) ? inv_dy : 0.5f * inv_dy;
                a3_new.x = s2c.x + DT_S * (-(u5.x * ((s2c.y - cL  ) * sxx) + g5.x * ((yh.x - yl.x) * sy)) * m5.x);
                a3_new.y = s2c.y + DT_S * (-(u5.y * ((s2c.z - s2c.x) * sxh) + g5.y * ((yh.y - yl.y) * sy)) * m5.y);
                a3_new.z = s2c.z + DT_S * (-(u5.z * ((s2c.w - s2c.y) * sxh) + g5.z * ((yh.z - yl.z) * sy)) * m5.z);
                a3_new.w = s2c.w + DT_S * (-(u5.w * ((cR   - s2c.z) * sxw) + g5.w * ((yh.w - yl.w) * sy)) * m5.w);
            }
            if (isL) eA3[rg_am4][wv][0] = a3_new.x;
            if (isR) eA3[rg_am4][wv][1] = a3_new.w;
        }
        s2p = s2c; s2c = s2n;
        a3n = a3_new;

        // B3: A3 edges visible
        asm volatile("s_waitcnt lgkmcnt(0)" ::: "memory");
        __builtin_amdgcn_s_barrier();

        // ---------------- out: smooth A3 at row a-5 ----------------
        if (j >= 10) {
            const int r = a - 5;                 // in [h0, h0+SH3)
            if (r < H) {
                float4 v;
                v.x = a3p.x + 2.f * a3c.x + a3n.x;
                v.y = a3p.y + 2.f * a3c.y + a3n.y;
                v.z = a3p.z + 2.f * a3c.z + a3n.z;
                v.w = a3p.w + 2.f * a3c.w + a3n.w;
                float vL = __shfl_up(v.w, 1);
                float vR = __shfl_down(v.x, 1);
                if (isL) vL = domL ? 0.f
                    : (eA3[rg_am6][wv - 1][1] + 2.f * eA3[rg_am5][wv - 1][1] + eA3[rg_am4][wv - 1][1]);
                if (isR) vR = domR ? 0.f
                    : (eA3[rg_am6][wv + 1][0] + 2.f * eA3[rg_am5][wv + 1][0] + eA3[rg_am4][wv + 1][0]);
                float4 o;
                o.x = (vL  + 2.f * v.x + v.y) * 0.0625f * m6.x;
                o.y = (v.x + 2.f * v.y + v.z) * 0.0625f * m6.y;
                o.z = (v.y + 2.f * v.z + v.w) * 0.0625f * m6.z;
                o.w = (v.z + 2.f * v.w + vR ) * 0.0625f * m6.w;
                *(float4*)(To + (size_t)r * W + gw) = o;
            }
        }
        a3p = a3c; a3c = a3n;
    }
}

// --------- legacy single-step stream kernel (fallback, W % 256 == 0) -------
__global__ __launch_bounds__(256, 4)
void stream_kernel(const float* __restrict__ Tin, const float* __restrict__ ug,
                   const float* __restrict__ vg, const float* __restrict__ mask,
                   const float* __restrict__ coef, float* __restrict__ Tout,
                   int H, int W) {
    const int lane = threadIdx.x & 63;
    const int wv   = threadIdx.x >> 6;
    const int ws   = blockIdx.x * WPW;
    const int hs   = (blockIdx.y * 4 + wv) * STRIP;
    const int b    = blockIdx.z;
    if (hs >= H) return;
    const size_t plane = (size_t)H * W;
    const float* __restrict__ Tb  = Tin + b * plane;
    const float* __restrict__ ugb = ug  + b * plane;
    const float* __restrict__ vgb = vg  + b * plane;
    float* __restrict__ To = Tout + b * plane;
    const float inv_dy = coef[H];
    const bool atL = (ws == 0);
    const bool atR = (ws + WPW >= W);
    const bool isL = (lane == 0);
    const bool isR = (lane == 63);
    const int gw = ws + 4 * lane;

    auto clampr = [&](int r) { return min(max(r, 0), H - 1); };
    auto ldT = [&](int r) -> float4 {
        return *(const float4*)(Tb + (size_t)clampr(r) * W + gw);
    };
    auto ldL = [&](int r) -> float2 {
        float4 q = *(const float4*)(Tb + (size_t)clampr(r) * W + (ws - 4));
        return make_float2(q.z, q.w);
    };
    auto ldR = [&](int r) -> float2 {
        float4 q = *(const float4*)(Tb + (size_t)clampr(r) * W + (ws + WPW));
        return make_float2(q.x, q.y);
    };

    float4 tp, tc, tn;
    float  tLp_w = 0.f; float2 tLc = make_float2(0.f, 0.f), tLn = make_float2(0.f, 0.f);
    float  tRp_x = 0.f; float2 tRc = make_float2(0.f, 0.f), tRn = make_float2(0.f, 0.f);

    auto roll = [&](int rnext) {
        tp = tc; tc = tn; tn = ldT(rnext);
        if (!atL) { tLp_w = tLc.y; tLc = tLn; tLn = ldL(rnext); }
        if (!atR) { tRp_x = tRc.x; tRc = tRn; tRn = ldR(rnext); }
    };

    auto advrow = [&](int r, float4& a, float& aL, float& aR, float4& mOut) {
        if (r < 0 || r >= H) {
            a = make_float4(0.f, 0.f, 0.f, 0.f); aL = 0.f; aR = 0.f;
            mOut = make_float4(0.f, 0.f, 0.f, 0.f); return;
        }
        const size_t ro = (size_t)r * W;
        const float ix  = coef[r];
        const float sy  = (r == 0 || r == H - 1) ? inv_dy : 0.5f * inv_dy;
        const float sxh = 0.5f * ix;
        float4 u4 = *(const float4*)(ugb + ro + gw);
        float4 g4 = *(const float4*)(vgb + ro + gw);
        float4 m4 = *(const float4*)(mask + ro + gw);
        float cLw = __shfl_up(tc.w, 1);
        float cRx = __shfl_down(tc.x, 1);
        float sxx = sxh, sxw = sxh;
        if (isL) { if (atL) { cLw = tc.x; sxx = ix; } else { cLw = tLc.y; } }
        if (isR) { if (atR) { cRx = tc.w; sxw = ix; } else { cRx = tRc.x; } }
        a.x = tc.x + DT_S * (-(u4.x * ((tc.y - cLw) * sxx) + g4.x * ((tn.x - tp.x) * sy)) * m4.x);
        a.y = tc.y + DT_S * (-(u4.y * ((tc.z - tc.x) * sxh) + g4.y * ((tn.y - tp.y) * sy)) * m4.y);
        a.z = tc.z + DT_S * (-(u4.z * ((tc.w - tc.y) * sxh) + g4.z * ((tn.z - tp.z) * sy)) * m4.z);
        a.w = tc.w + DT_S * (-(u4.w * ((cRx - tc.z) * sxw) + g4.w * ((tn.w - tp.w) * sy)) * m4.w);
        if (!atL) {
            float uL = ((const float4*)(ugb + ro + (ws - 4)))->w;
            float gL = ((const float4*)(vgb + ro + (ws - 4)))->w;
            float mL = ((const float4*)(mask + ro + (ws - 4)))->w;
            aL = tLc.y + DT_S * (-(uL * ((tc.x - tLc.x) * sxh) + gL * ((tLn.y - tLp_w) * sy)) * mL);
        } else aL = 0.f;
        if (!atR) {
            float uR = ((const float4*)(ugb + ro + (ws + WPW)))->x;
            float gR = ((const float4*)(vgb + ro + (ws + WPW)))->x;
            float mR = ((const float4*)(mask + ro + (ws + WPW)))->x;
            aR = tRc.x + DT_S * (-(uR * ((tRc.y - tc.w) * sxh) + gR * ((tRn.x - tRp_x) * sy)) * mR);
        } else aR = 0.f;
        mOut = m4;
    };

    tp = ldT(hs - 2); tc = ldT(hs - 1); tn = ldT(hs);
    if (!atL) { float2 q = ldL(hs - 2); tLp_w = q.y; tLc = ldL(hs - 1); tLn = ldL(hs); }
    if (!atR) { float2 q = ldR(hs - 2); tRp_x = q.x; tRc = ldR(hs - 1); tRn = ldR(hs); }

    float4 ap, ac, an, mC, mN, mdum;
    float aLp, aLc, aLn, aRp, aRc, aRn;
    advrow(hs - 1, ap, aLp, aRp, mdum);
    roll(hs + 1);
    advrow(hs, ac, aLc, aRc, mC);

    #pragma unroll
    for (int i = 0; i < STRIP; ++i) {
        const int go = hs + i;
        roll(go + 2);
        advrow(go + 1, an, aLn, aRn, mN);
        if (go < H) {
            float4 v;
            v.x = ap.x + 2.f * ac.x + an.x;
            v.y = ap.y + 2.f * ac.y + an.y;
            v.z = ap.z + 2.f * ac.z + an.z;
            v.w = ap.w + 2.f * ac.w + an.w;
            float vL  = aLp + 2.f * aLc + aLn;
            float vR  = aRp + 2.f * aRc + aRn;
            float vLw = __shfl_up(v.w, 1);
            float vRx = __shfl_down(v.x, 1);
            if (isL) vLw = atL ? 0.f : vL;
            if (isR) vRx = atR ? 0.f : vR;
            float4 o;
            o.x = (vLw + 2.f * v.x + v.y) * 0.0625f * mC.x;
            o.y = (v.x + 2.f * v.y + v.z) * 0.0625f * mC.y;
            o.z = (v.y + 2.f * v.z + v.w) * 0.0625f * mC.z;
            o.w = (v.z + 2.f * v.w + vRx) * 0.0625f * mC.w;
            *(float4*)(To + (size_t)go * W + gw) = o;
        }
        ap = ac; ac = an;
        aLp = aLc; aLc = aLn; aRp = aRc; aRc = aRn;
        mC = mN;
    }
}

// ---------- generic fallback (round-1 LDS tile kernel, validated) ----------
constexpr int FTW = 64, FTH = 32;
constexpr int FSTW = FTW + 4, FSTH = FTH + 4;
constexpr int FMTW = FTW + 2, FMTH = FTH + 2;

__global__ __launch_bounds__(256)
void step_tile(const float* __restrict__ Tin, const float* __restrict__ ug,
               const float* __restrict__ vg, const float* __restrict__ mask,
               const float* __restrict__ coef, float* __restrict__ Tout,
               int H, int W) {
    __shared__ float sT[FSTH][FSTW];
    __shared__ float sM[FMTH][FMTW];
    const int tid = threadIdx.x;
    const int w0 = blockIdx.x * FTW;
    const int h0 = blockIdx.y * FTH;
    const int b  = blockIdx.z;
    const long plane = (long)H * W;
    const float* Tb  = Tin + b * plane;
    const float* ugb = ug  + b * plane;
    const float* vgb = vg  + b * plane;
    const float inv_dy = coef[H];

    for (int i = tid; i < FSTH * FSTW; i += NT) {
        int r = i / FSTW, c = i - r * FSTW;
        int gh = min(max(h0 - 2 + r, 0), H - 1);
        int gw = min(max(w0 - 2 + c, 0), W - 1);
        sT[r][c] = Tb[gh * W + gw];
    }
    __syncthreads();
    for (int i = tid; i < FMTH * FMTW; i += NT) {
        int r = i / FMTW, c = i - r * FMTW;
        int gh = h0 - 1 + r, gw = w0 - 1 + c;
        float v = 0.0f;
        if (gh >= 0 && gh < H && gw >= 0 && gw < W) {
            int sr = r + 1, sc = c + 1;
            float ndy = sT[sr + 1][sc] - sT[sr - 1][sc];
            float ndx = sT[sr][sc + 1] - sT[sr][sc - 1];
            float sy  = (gh == 0 || gh == H - 1) ? inv_dy : 0.5f * inv_dy;
            float ix  = coef[gh];
            float sx  = (gw == 0 || gw == W - 1) ? ix : 0.5f * ix;
            int   gi  = gh * W + gw;
            float F   = -(ugb[gi] * (ndx * sx) + vgb[gi] * (ndy * sy)) * mask[gi];
            v = sT[sr][sc] + DT_S * F;
        }
        sM[r][c] = v;
    }
    __syncthreads();
    float* To = Tout + b * plane;
    for (int i = tid; i < FTH * FTW; i += NT) {
        int r = i >> 6, c = i & (FTW - 1);
        int gh = h0 + r, gw = w0 + c;
        if (gh < H && gw < W) {
            int sr = r + 1, sc = c + 1;
            float s = (sM[sr-1][sc-1] + sM[sr-1][sc+1] + sM[sr+1][sc-1] + sM[sr+1][sc+1])
                    + 2.0f * (sM[sr-1][sc] + sM[sr+1][sc] + sM[sr][sc-1] + sM[sr][sc+1])
                    + 4.0f * sM[sr][sc];
            To[gh * W + gw] = s * 0.0625f * mask[gh * W + gw];
        }
    }
}

extern "C" void kernel_launch(void* const* d_in, const int* in_sizes, int n_in,
                              void* d_out, int out_size, void* d_ws, size_t ws_size,
                              hipStream_t stream) {
    const float* T0   = (const float*)d_in[0];
    const float* ug   = (const float*)d_in[1];
    const float* vg   = (const float*)d_in[2];
    const float* lat  = (const float*)d_in[3];
    const float* lon  = (const float*)d_in[4];
    const float* mask = (const float*)d_in[5];

    const int H = in_sizes[3];
    const int W = in_sizes[4];
    const int B = in_sizes[0] / (H * W);

    float* out  = (float*)d_out;
    float* ping = (float*)d_ws;                 // B*H*W floats
    float* coef = ping + (size_t)B * H * W;     // H+1 floats: 1/dx[h], then 1/dy

    prep_kernel<<<dim3((H + NT - 1) / NT), dim3(NT), 0, stream>>>(lat, lon, coef, H);

    const int STEPS = 48;

    if (W == FWAVES * 256) {
        // fused 3-step path: 16 launches, each = 3 simulated steps
        dim3 gridF3((H + SH3 - 1) / SH3, B);
        const int NLAUNCH = STEPS / 3;          // 16, even -> last dst == out
        for (int i = 0; i < NLAUNCH; ++i) {
            const float* src = (i == 0) ? T0 : ((i & 1) ? ping : out);
            float*       dst = (i & 1) ? out : ping;
            fused3_kernel<<<gridF3, dim3(NT), 0, stream>>>(src, ug, vg, mask, coef, dst, H, W);
        }
    } else {
        const bool fast = (W % WPW) == 0;
        dim3 gridS(W / (fast ? WPW : 1), (H + 4 * STRIP - 1) / (4 * STRIP), B);
        dim3 gridF((W + FTW - 1) / FTW, (H + FTH - 1) / FTH, B);
        for (int i = 0; i < STEPS; ++i) {
            const float* src = (i == 0) ? T0 : ((i & 1) ? ping : out);
            float*       dst = (i & 1) ? out : ping;
            if (fast)
                stream_kernel<<<gridS, dim3(NT), 0, stream>>>(src, ug, vg, mask, coef, dst, H, W);
            else
                step_tile<<<gridF, dim3(NT), 0, stream>>>(src, ug, vg, mask, coef, dst, H, W);
        }
    }
}